// Round 4
// baseline (448.910 us; speedup 1.0000x reference)
//
#include <hip/hip_runtime.h>
#include <hip/hip_bf16.h>
#include <math.h>

// B=32, H=64, W=64, C_IN=384, C_HID=128
// conv3x3(pad1)+b1 -> relu -> conv1x1+b2 -> sigmoid, NHWC fp32.
// Implicit GEMM, halo-LDS (double-buffered), tap-sharing:
//   per block: 16x8 output pixels (M=128), N=128, K=9*384.
//   chunk loop (12 x 32ch): LDS dbuf -> ONE barrier/chunk; staged halo is
//   register-prefetched 2 chunks ahead; per-ox 6 B-frags issued before their
//   MFMAs; sreg HBM prefetch issued after all B issues (vmcnt FIFO order).

typedef __attribute__((ext_vector_type(8))) unsigned short ushort8;
typedef __attribute__((ext_vector_type(8))) __bf16 bf16x8;
typedef __attribute__((ext_vector_type(4))) float floatx4;

static __device__ __forceinline__ unsigned short f2bf_rne(float f) {
  union { float f; unsigned int u; } x; x.f = f;
  unsigned int u = x.u;
  return (unsigned short)((u + 0x7fffu + ((u >> 16) & 1u)) >> 16);
}

static __device__ __forceinline__ ushort8 pack8(const float* v) {
  ushort8 r;
#pragma unroll
  for (int i = 0; i < 4; ++i) {
    __hip_bfloat162 p = __float22bfloat162_rn(make_float2(v[2 * i], v[2 * i + 1]));
    union { __hip_bfloat162 b; unsigned int u; } c;
    c.b = p;
    r[2 * i] = (unsigned short)(c.u & 0xffffu);
    r[2 * i + 1] = (unsigned short)(c.u >> 16);
  }
  return r;
}

// W1 (3,3,384,128 HWIO fp32) -> bf16 W1b[kk][n][c], kk=o*12+chunk, n=0..127, c=0..31.
__global__ void prep_w1_kernel(const float* __restrict__ W1,
                               unsigned short* __restrict__ W1b) {
  __shared__ unsigned short tile[32 * 128];
  const int kk = blockIdx.x;            // 0..107
  const int o = kk / 12;
  const int chunk = kk - o * 12;
  const float* src = W1 + (o * 384 + chunk * 32) * 128;  // [c][n], n contiguous
  const int t = threadIdx.x;
#pragma unroll
  for (int i = 0; i < 16; ++i) {
    int idx = t + i * 256;              // idx = c*128+n
    int c = idx >> 7;
    int n = idx & 127;
    tile[n * 32 + c] = f2bf_rne(src[idx]);
  }
  __syncthreads();
  unsigned short* dst = W1b + kk * 4096;
#pragma unroll
  for (int i = 0; i < 16; ++i) {
    int idx = t + i * 256;
    dst[idx] = tile[idx];
  }
}

__global__ __launch_bounds__(256, 4) void conv_fused_kernel(
    const float* __restrict__ x, const unsigned short* __restrict__ W1b,
    const float* __restrict__ b1, const float* __restrict__ W2,
    const float* __restrict__ b2, float* __restrict__ out) {
  // Halo: 10 rows x 18 cols x 32 ch bf16, pixel stride 40 elems; DOUBLE buffered.
  __shared__ alignas(16) unsigned short Ah[2 * 7200];  // 28800 B
  __shared__ float hsum[128 * 4];                      // 2048 B

  const int t = threadIdx.x;
  const int w = t >> 6;        // wave 0..3 -> n block [32w, 32w+32)
  const int lane = t & 63;
  const int g = lane >> 4;     // quad
  const int lr = lane & 15;

  const int img = blockIdx.x >> 5;       // 32 images
  const int tileId = blockIdx.x & 31;    // 8x4 grid of 8(tall)x16(wide) tiles
  const int ty0 = (tileId >> 2) << 3;
  const int tx0 = (tileId & 3) << 4;

  // ---- staging plan: 720 items (halo px 0..179 x sub 0..3), 8 ch each ----
  int svalid[3];
  int soff[3];   // element offset into x (32-bit, saves VGPRs vs pointers)
  int sloff[3];  // LDS element offset within one buffer
  const bool act2 = t < 208;
#pragma unroll
  for (int j = 0; j < 3; ++j) {
    int i = t + j * 256;
    int px = i >> 2, sub = i & 3;
    int hy = (px * 57) >> 10;            // px/18 for px<1024
    int hx = px - hy * 18;
    int iy = ty0 + hy - 1, ix = tx0 + hx - 1;
    int v = ((unsigned)iy < 64u) && ((unsigned)ix < 64u);
    if (j == 2 && !act2) v = 0;
    svalid[j] = v;
    int iyc = v ? iy : 0, ixc = v ? ix : 0;
    soff[j] = ((((img << 6) + iyc) << 6) + ixc) * 384 + sub * 8;
    sloff[j] = px * 40 + sub * 8;
  }

  // B frag offset (elems): row n = w*32 + lr (+16 for ni=1), k-sub = g*8
  const int boff = ((w * 32 + lr) << 5) + (g << 3);
  // A frag lane part (elems): col lr, quad k-sub
  const int aoffl = lr * 40 + (g << 3);

  floatx4 acc[8][2] = {};  // pixel row = mi, pixel col = g*4+r, ch n = w*32+ni*16+lr

  const float b1v0 = b1[w * 32 + lr];
  const float b1v1 = b1[w * 32 + 16 + lr];
  const float w2v0 = W2[w * 32 + lr];
  const float w2v1 = W2[w * 32 + 16 + lr];

  float sreg[3][8];
#pragma unroll
  for (int j = 0; j < 3; ++j)
#pragma unroll
    for (int e = 0; e < 8; ++e) sreg[j][e] = 0.0f;

  // ---- prologue: chunk 0 -> sreg -> buf0; issue chunk 1 -> sreg ----
#pragma unroll
  for (int j = 0; j < 3; ++j) {
    if (svalid[j]) {
      *(float4*)&sreg[j][0] = *(const float4*)(x + soff[j]);
      *(float4*)&sreg[j][4] = *(const float4*)(x + soff[j] + 4);
    }
  }
  *(ushort8*)&Ah[sloff[0]] = pack8(sreg[0]);
  *(ushort8*)&Ah[sloff[1]] = pack8(sreg[1]);
  if (act2) *(ushort8*)&Ah[sloff[2]] = pack8(sreg[2]);
#pragma unroll
  for (int j = 0; j < 3; ++j) {
    if (svalid[j]) {
      *(float4*)&sreg[j][0] = *(const float4*)(x + soff[j] + 32);
      *(float4*)&sreg[j][4] = *(const float4*)(x + soff[j] + 36);
    }
  }
  __syncthreads();

  for (int c = 0; c < 12; ++c) {
    const int rb = (c & 1) * 7200;        // read buffer (holds chunk c)
    const int wb = 7200 - rb;             // write buffer (gets chunk c+1)

    // stage chunk c+1 (already in sreg) into the other buffer
    if (c < 11) {
      *(ushort8*)&Ah[wb + sloff[0]] = pack8(sreg[0]);
      *(ushort8*)&Ah[wb + sloff[1]] = pack8(sreg[1]);
      if (act2) *(ushort8*)&Ah[wb + sloff[2]] = pack8(sreg[2]);
    }

    // compute chunk c from rb; B issued per-ox before use; sreg prefetch LAST
#pragma unroll
    for (int ox = 0; ox < 3; ++ox) {
      bf16x8 bf[3][2];
#pragma unroll
      for (int oy = 0; oy < 3; ++oy) {
        const unsigned short* bp =
            W1b + ((((oy * 3 + ox) * 12 + c) << 12)) + boff;
        bf[oy][0] = *(const bf16x8*)bp;
        bf[oy][1] = *(const bf16x8*)(bp + 512);
      }
      if (ox == 2 && c < 10) {
        const int off = (c + 2) << 5;
#pragma unroll
        for (int j = 0; j < 3; ++j) {
          if (svalid[j]) {
            *(float4*)&sreg[j][0] = *(const float4*)(x + soff[j] + off);
            *(float4*)&sreg[j][4] = *(const float4*)(x + soff[j] + off + 4);
          }
        }
      }
#pragma unroll
      for (int h = 0; h < 10; ++h) {
        const bf16x8 af = *(const bf16x8*)&Ah[rb + h * 720 + ox * 40 + aoffl];
#pragma unroll
        for (int oy = 0; oy < 3; ++oy) {
          const int mi = h - oy;
          if (mi >= 0 && mi < 8) {
            acc[mi][0] = __builtin_amdgcn_mfma_f32_16x16x32_bf16(
                af, bf[oy][0], acc[mi][0], 0, 0, 0);
            acc[mi][1] = __builtin_amdgcn_mfma_f32_16x16x32_bf16(
                af, bf[oy][1], acc[mi][1], 0, 0, 0);
          }
        }
      }
    }
    __syncthreads();
  }

  // ---- epilogue: bias+relu, conv1x1 reduce over n, sigmoid ----
#pragma unroll
  for (int mi = 0; mi < 8; ++mi) {
#pragma unroll
    for (int r = 0; r < 4; ++r) {
      float h0 = fmaxf(acc[mi][0][r] + b1v0, 0.0f);
      float h1 = fmaxf(acc[mi][1][r] + b1v1, 0.0f);
      float v = h0 * w2v0 + h1 * w2v1;
      v += __shfl_xor(v, 1);
      v += __shfl_xor(v, 2);
      v += __shfl_xor(v, 4);
      v += __shfl_xor(v, 8);
      if (lr == 0) {
        int m = mi * 16 + g * 4 + r;  // pixel row = mi, pixel col = g*4+r
        hsum[m * 4 + w] = v;
      }
    }
  }
  __syncthreads();
  if (t < 128) {
    float s = hsum[t * 4 + 0] + hsum[t * 4 + 1] + hsum[t * 4 + 2] +
              hsum[t * 4 + 3] + b2[0];
    float sig = 1.0f / (1.0f + expf(-s));
    int prow = t >> 4, pcol = t & 15;
    out[((((img << 6) + ty0 + prow) << 6) + tx0 + pcol)] = sig;
  }
}

extern "C" void kernel_launch(void* const* d_in, const int* in_sizes, int n_in,
                              void* d_out, int out_size, void* d_ws, size_t ws_size,
                              hipStream_t stream) {
  const float* x  = (const float*)d_in[0];   // (32,64,64,384)
  const float* W1 = (const float*)d_in[1];   // (3,3,384,128)
  const float* b1 = (const float*)d_in[2];   // (128)
  const float* W2 = (const float*)d_in[3];   // (128)
  const float* b2 = (const float*)d_in[4];   // (1)
  float* out = (float*)d_out;                // (32,64,64,1)
  unsigned short* W1b = (unsigned short*)d_ws;  // 108*4096*2 = 884736 B

  prep_w1_kernel<<<108, 256, 0, stream>>>(W1, W1b);
  conv_fused_kernel<<<1024, 256, 0, stream>>>(x, W1b, b1, W2, b2, out);
}

// Round 5
// 374.087 us; speedup vs baseline: 1.2000x; 1.2000x over previous
//
#include <hip/hip_runtime.h>
#include <hip/hip_bf16.h>
#include <math.h>

// B=32, H=64, W=64, C_IN=384, C_HID=128
// conv3x3(pad1)+b1 -> relu -> conv1x1+b2 -> sigmoid, NHWC fp32.
// Implicit GEMM, halo-LDS (double-buffered), tap-sharing:
//   per block: 4x16 output pixels (M=64), N=128, K=9*384. Grid 2048 (8 blk/CU
//   worth of queue; ~4 resident by VGPR). chunk loop (12 x 32ch): ONE barrier
//   per chunk; halo (6x18 px x 32ch bf16) staged via regs prefetched 2 chunks
//   ahead; per-ox 6 B-frags from global (L2) before their MFMAs.

typedef __attribute__((ext_vector_type(8))) unsigned short ushort8;
typedef __attribute__((ext_vector_type(8))) __bf16 bf16x8;
typedef __attribute__((ext_vector_type(4))) float floatx4;

static __device__ __forceinline__ unsigned short f2bf_rne(float f) {
  union { float f; unsigned int u; } x; x.f = f;
  unsigned int u = x.u;
  return (unsigned short)((u + 0x7fffu + ((u >> 16) & 1u)) >> 16);
}

static __device__ __forceinline__ ushort8 pack8(const float* v) {
  ushort8 r;
#pragma unroll
  for (int i = 0; i < 4; ++i) {
    __hip_bfloat162 p = __float22bfloat162_rn(make_float2(v[2 * i], v[2 * i + 1]));
    union { __hip_bfloat162 b; unsigned int u; } c;
    c.b = p;
    r[2 * i] = (unsigned short)(c.u & 0xffffu);
    r[2 * i + 1] = (unsigned short)(c.u >> 16);
  }
  return r;
}

// W1 (3,3,384,128 HWIO fp32) -> bf16 W1b[kk][n][c], kk=o*12+chunk, n=0..127, c=0..31.
__global__ void prep_w1_kernel(const float* __restrict__ W1,
                               unsigned short* __restrict__ W1b) {
  __shared__ unsigned short tile[32 * 128];
  const int kk = blockIdx.x;            // 0..107
  const int o = kk / 12;
  const int chunk = kk - o * 12;
  const float* src = W1 + (o * 384 + chunk * 32) * 128;  // [c][n], n contiguous
  const int t = threadIdx.x;
#pragma unroll
  for (int i = 0; i < 16; ++i) {
    int idx = t + i * 256;              // idx = c*128+n
    int c = idx >> 7;
    int n = idx & 127;
    tile[n * 32 + c] = f2bf_rne(src[idx]);
  }
  __syncthreads();
  unsigned short* dst = W1b + kk * 4096;
#pragma unroll
  for (int i = 0; i < 16; ++i) {
    int idx = t + i * 256;
    dst[idx] = tile[idx];
  }
}

__global__ __launch_bounds__(256) void conv_fused_kernel(
    const float* __restrict__ x, const unsigned short* __restrict__ W1b,
    const float* __restrict__ b1, const float* __restrict__ W2,
    const float* __restrict__ b2, float* __restrict__ out) {
  // Halo: 6 rows x 18 cols x 32 ch bf16, pixel stride 40 elems; DOUBLE buffered.
  __shared__ alignas(16) unsigned short Ah[2 * 4320];  // 17280 B
  __shared__ float hsum[64 * 4];                       // 1024 B

  const int t = threadIdx.x;
  const int w = t >> 6;        // wave 0..3 -> n block [32w, 32w+32)
  const int lane = t & 63;
  const int g = lane >> 4;     // quad
  const int lr = lane & 15;

  const int img = blockIdx.x >> 6;       // 32 images
  const int tileId = blockIdx.x & 63;    // 16x4 grid of 4(tall)x16(wide) tiles
  const int ty0 = (tileId >> 2) << 2;
  const int tx0 = (tileId & 3) << 4;

  // ---- staging plan: 432 items (halo px 0..107 x sub 0..3), 8 ch each ----
  // items: t, t+256 (active if t<176)
  int svalid[2];
  int soff[2];   // element offset into x
  int sloff[2];  // LDS element offset within one buffer
  const bool act1 = t < 176;
#pragma unroll
  for (int j = 0; j < 2; ++j) {
    int i = t + j * 256;
    int px = i >> 2, sub = i & 3;
    int hy = (px * 57) >> 10;            // px/18 for px<1024
    int hx = px - hy * 18;
    int iy = ty0 + hy - 1, ix = tx0 + hx - 1;
    int v = ((unsigned)iy < 64u) && ((unsigned)ix < 64u);
    if (j == 1 && !act1) v = 0;
    svalid[j] = v;
    int iyc = v ? iy : 0, ixc = v ? ix : 0;
    soff[j] = ((((img << 6) + iyc) << 6) + ixc) * 384 + sub * 8;
    sloff[j] = px * 40 + sub * 8;
  }

  // B frag offset (elems): row n = w*32 + lr (+16 for ni=1), k-sub = g*8
  const int boff = ((w * 32 + lr) << 5) + (g << 3);
  // A frag lane part (elems): halo col lr (+ox), quad k-sub g*8
  const int aoffl = lr * 40 + (g << 3);

  floatx4 acc[4][2] = {};  // pixel row = mi, pixel col = g*4+r, ch n = w*32+ni*16+lr

  const float b1v0 = b1[w * 32 + lr];
  const float b1v1 = b1[w * 32 + 16 + lr];
  const float w2v0 = W2[w * 32 + lr];
  const float w2v1 = W2[w * 32 + 16 + lr];

  float sreg[2][8];
#pragma unroll
  for (int j = 0; j < 2; ++j)
#pragma unroll
    for (int e = 0; e < 8; ++e) sreg[j][e] = 0.0f;

  // ---- prologue: chunk 0 -> sreg -> buf0; issue chunk 1 -> sreg ----
#pragma unroll
  for (int j = 0; j < 2; ++j) {
    if (svalid[j]) {
      *(float4*)&sreg[j][0] = *(const float4*)(x + soff[j]);
      *(float4*)&sreg[j][4] = *(const float4*)(x + soff[j] + 4);
    }
  }
  *(ushort8*)&Ah[sloff[0]] = pack8(sreg[0]);
  if (act1) *(ushort8*)&Ah[sloff[1]] = pack8(sreg[1]);
#pragma unroll
  for (int j = 0; j < 2; ++j) {
    if (svalid[j]) {
      *(float4*)&sreg[j][0] = *(const float4*)(x + soff[j] + 32);
      *(float4*)&sreg[j][4] = *(const float4*)(x + soff[j] + 36);
    }
  }
  __syncthreads();

  for (int c = 0; c < 12; ++c) {
    const int rb = (c & 1) * 4320;        // read buffer (holds chunk c)
    const int wb = 4320 - rb;             // write buffer (gets chunk c+1)

    // stage chunk c+1 (already in sreg) into the other buffer
    if (c < 11) {
      *(ushort8*)&Ah[wb + sloff[0]] = pack8(sreg[0]);
      if (act1) *(ushort8*)&Ah[wb + sloff[1]] = pack8(sreg[1]);
    }

    // compute chunk c from rb; B issued per-ox before use; sreg prefetch after
#pragma unroll
    for (int ox = 0; ox < 3; ++ox) {
      bf16x8 bf[3][2];
#pragma unroll
      for (int oy = 0; oy < 3; ++oy) {
        const unsigned short* bp =
            W1b + ((((oy * 3 + ox) * 12 + c) << 12)) + boff;
        bf[oy][0] = *(const bf16x8*)bp;
        bf[oy][1] = *(const bf16x8*)(bp + 512);
      }
      if (ox == 2 && c < 10) {
        const int off = (c + 2) << 5;
#pragma unroll
        for (int j = 0; j < 2; ++j) {
          if (svalid[j]) {
            *(float4*)&sreg[j][0] = *(const float4*)(x + soff[j] + off);
            *(float4*)&sreg[j][4] = *(const float4*)(x + soff[j] + off + 4);
          }
        }
      }
#pragma unroll
      for (int h = 0; h < 6; ++h) {
        const bf16x8 af = *(const bf16x8*)&Ah[rb + h * 720 + ox * 40 + aoffl];
#pragma unroll
        for (int oy = 0; oy < 3; ++oy) {
          const int mi = h - oy;
          if (mi >= 0 && mi < 4) {
            acc[mi][0] = __builtin_amdgcn_mfma_f32_16x16x32_bf16(
                af, bf[oy][0], acc[mi][0], 0, 0, 0);
            acc[mi][1] = __builtin_amdgcn_mfma_f32_16x16x32_bf16(
                af, bf[oy][1], acc[mi][1], 0, 0, 0);
          }
        }
      }
    }
    __syncthreads();
  }

  // ---- epilogue: bias+relu, conv1x1 reduce over n, sigmoid ----
#pragma unroll
  for (int mi = 0; mi < 4; ++mi) {
#pragma unroll
    for (int r = 0; r < 4; ++r) {
      float h0 = fmaxf(acc[mi][0][r] + b1v0, 0.0f);
      float h1 = fmaxf(acc[mi][1][r] + b1v1, 0.0f);
      float v = h0 * w2v0 + h1 * w2v1;
      v += __shfl_xor(v, 1);
      v += __shfl_xor(v, 2);
      v += __shfl_xor(v, 4);
      v += __shfl_xor(v, 8);
      if (lr == 0) {
        int m = mi * 16 + g * 4 + r;  // pixel row = mi, pixel col = g*4+r
        hsum[m * 4 + w] = v;
      }
    }
  }
  __syncthreads();
  if (t < 64) {
    float s = hsum[t * 4 + 0] + hsum[t * 4 + 1] + hsum[t * 4 + 2] +
              hsum[t * 4 + 3] + b2[0];
    float sig = 1.0f / (1.0f + expf(-s));
    int prow = t >> 4, pcol = t & 15;
    out[((((img << 6) + ty0 + prow) << 6) + tx0 + pcol)] = sig;
  }
}

extern "C" void kernel_launch(void* const* d_in, const int* in_sizes, int n_in,
                              void* d_out, int out_size, void* d_ws, size_t ws_size,
                              hipStream_t stream) {
  const float* x  = (const float*)d_in[0];   // (32,64,64,384)
  const float* W1 = (const float*)d_in[1];   // (3,3,384,128)
  const float* b1 = (const float*)d_in[2];   // (128)
  const float* W2 = (const float*)d_in[3];   // (128)
  const float* b2 = (const float*)d_in[4];   // (1)
  float* out = (float*)d_out;                // (32,64,64,1)
  unsigned short* W1b = (unsigned short*)d_ws;  // 108*4096*2 = 884736 B

  prep_w1_kernel<<<108, 256, 0, stream>>>(W1, W1b);
  conv_fused_kernel<<<2048, 256, 0, stream>>>(x, W1b, b1, W2, b2, out);
}

// Round 6
// 373.130 us; speedup vs baseline: 1.2031x; 1.0026x over previous
//
#include <hip/hip_runtime.h>
#include <hip/hip_bf16.h>
#include <math.h>

// B=32, H=64, W=64, C_IN=384, C_HID=128
// conv3x3(pad1)+b1 -> relu -> conv1x1+b2 -> sigmoid, NHWC fp32.
// Implicit GEMM, halo-LDS (double-buffered, conflict-free [g][px][8] layout),
// tap-sharing, B-frags software-pipelined one ox-batch ahead (ping-pong regs).
//   per block: 4x16 output pixels (M=64), N=128, K=9*384. Grid 2048.
//   chunk loop (12 x 32ch) FULLY UNROLLED: one barrier/chunk; halo staged from
//   regs prefetched 2 chunks ahead; B batch (6 frags) prefetched 1 ox ahead.

typedef __attribute__((ext_vector_type(8))) unsigned short ushort8;
typedef __attribute__((ext_vector_type(8))) __bf16 bf16x8;
typedef __attribute__((ext_vector_type(4))) float floatx4;

static __device__ __forceinline__ unsigned short f2bf_rne(float f) {
  union { float f; unsigned int u; } x; x.f = f;
  unsigned int u = x.u;
  return (unsigned short)((u + 0x7fffu + ((u >> 16) & 1u)) >> 16);
}

static __device__ __forceinline__ ushort8 pack8(const float* v) {
  ushort8 r;
#pragma unroll
  for (int i = 0; i < 4; ++i) {
    __hip_bfloat162 p = __float22bfloat162_rn(make_float2(v[2 * i], v[2 * i + 1]));
    union { __hip_bfloat162 b; unsigned int u; } c;
    c.b = p;
    r[2 * i] = (unsigned short)(c.u & 0xffffu);
    r[2 * i + 1] = (unsigned short)(c.u >> 16);
  }
  return r;
}

// W1 (3,3,384,128 HWIO fp32) -> bf16 W1b[kk][n][c], kk=o*12+chunk, n=0..127, c=0..31.
__global__ void prep_w1_kernel(const float* __restrict__ W1,
                               unsigned short* __restrict__ W1b) {
  __shared__ unsigned short tile[32 * 128];
  const int kk = blockIdx.x;            // 0..107
  const int o = kk / 12;
  const int chunk = kk - o * 12;
  const float* src = W1 + (o * 384 + chunk * 32) * 128;  // [c][n], n contiguous
  const int t = threadIdx.x;
#pragma unroll
  for (int i = 0; i < 16; ++i) {
    int idx = t + i * 256;              // idx = c*128+n
    int c = idx >> 7;
    int n = idx & 127;
    tile[n * 32 + c] = f2bf_rne(src[idx]);
  }
  __syncthreads();
  unsigned short* dst = W1b + kk * 4096;
#pragma unroll
  for (int i = 0; i < 16; ++i) {
    int idx = t + i * 256;
    dst[idx] = tile[idx];
  }
}

__global__ __launch_bounds__(256, 2) void conv_fused_kernel(
    const float* __restrict__ x, const unsigned short* __restrict__ W1b,
    const float* __restrict__ b1, const float* __restrict__ W2,
    const float* __restrict__ b2, float* __restrict__ out) {
  // Halo buffer layout: [buf][g 0..3][px 0..107][8 ch] bf16.
  //   elem off = buf*3456 + ((g*108 + px) << 3) + j.
  //   Reads (fixed g, lr 0..15 consecutive px) are 256B-contiguous per g-group;
  //   g-groups offset by 1728B -> every bank hit exactly 8x -> conflict-free.
  __shared__ alignas(16) unsigned short Ah[2 * 3456];  // 13824 B
  __shared__ float hsum[64 * 4];                       // 1024 B

  const int t = threadIdx.x;
  const int w = t >> 6;        // wave 0..3 -> n block [32w, 32w+32)
  const int lane = t & 63;
  const int g = lane >> 4;     // quad (k-sub)
  const int lr = lane & 15;

  const int img = blockIdx.x >> 6;       // 32 images
  const int tileId = blockIdx.x & 63;    // 16x4 grid of 4(tall)x16(wide) tiles
  const int ty0 = (tileId >> 2) << 2;
  const int tx0 = (tileId & 3) << 4;

  // ---- staging plan: 432 items (halo px 0..107 x sub 0..3), 8 ch each ----
  // items: t, t+256 (active if t<176). sub == g of the 8 staged channels.
  int svalid[2];
  int soff[2];   // element offset into x
  int sloff[2];  // LDS element offset within one buffer ([g][px][8] layout)
  const bool act1 = t < 176;
#pragma unroll
  for (int j = 0; j < 2; ++j) {
    int i = t + j * 256;
    int px = i >> 2, sub = i & 3;
    int hy = (px * 57) >> 10;            // px/18 for px<1024
    int hx = px - hy * 18;
    int iy = ty0 + hy - 1, ix = tx0 + hx - 1;
    int v = ((unsigned)iy < 64u) && ((unsigned)ix < 64u);
    if (j == 1 && !act1) v = 0;
    svalid[j] = v;
    int iyc = v ? iy : 0, ixc = v ? ix : 0;
    soff[j] = ((((img << 6) + iyc) << 6) + ixc) * 384 + sub * 8;
    sloff[j] = (sub * 108 + px) << 3;
  }

  // B frag offset (elems): row n = w*32 + lr (+16 for ni=1), k-sub = g*8
  const int boff = ((w * 32 + lr) << 5) + (g << 3);
  // A frag: offset = rb + ((g*108 + h*18 + ox + lr) << 3)
  const int aoffl = (g * 108 + lr) << 3;

  floatx4 acc[4][2] = {};  // pixel row = mi, pixel col = g*4+r, ch n = w*32+ni*16+lr

  const float b1v0 = b1[w * 32 + lr];
  const float b1v1 = b1[w * 32 + 16 + lr];
  const float w2v0 = W2[w * 32 + lr];
  const float w2v1 = W2[w * 32 + 16 + lr];

  float sreg[2][8];
#pragma unroll
  for (int j = 0; j < 2; ++j)
#pragma unroll
    for (int e = 0; e < 8; ++e) sreg[j][e] = 0.0f;

  // ---- prologue: chunk 0 -> sreg -> buf0; issue chunk 1 -> sreg ----
#pragma unroll
  for (int j = 0; j < 2; ++j) {
    if (svalid[j]) {
      *(float4*)&sreg[j][0] = *(const float4*)(x + soff[j]);
      *(float4*)&sreg[j][4] = *(const float4*)(x + soff[j] + 4);
    }
  }
  *(ushort8*)&Ah[sloff[0]] = pack8(sreg[0]);
  if (act1) *(ushort8*)&Ah[sloff[1]] = pack8(sreg[1]);
#pragma unroll
  for (int j = 0; j < 2; ++j) {
    if (svalid[j]) {
      *(float4*)&sreg[j][0] = *(const float4*)(x + soff[j] + 32);
      *(float4*)&sreg[j][4] = *(const float4*)(x + soff[j] + 36);
    }
  }

  // ---- B ping-pong: batch = 6 bf16x8 (3 oy x 2 ni) = 24 VGPRs each ----
  bf16x8 bf[2][3][2];
#pragma unroll
  for (int oy = 0; oy < 3; ++oy) {   // preload (c=0, ox=0) into bf[0]
    const unsigned short* bp = W1b + ((oy * 3 + 0) * 12 << 12) + boff;
    bf[0][oy][0] = *(const bf16x8*)bp;
    bf[0][oy][1] = *(const bf16x8*)(bp + 512);
  }
  __syncthreads();

#pragma unroll
  for (int c = 0; c < 12; ++c) {
    const int rb = (c & 1) * 3456;        // read buffer (holds chunk c)
    const int wb = 3456 - rb;             // write buffer (gets chunk c+1)

    // stage chunk c+1 (already in sreg) into the other buffer
    if (c < 11) {
      *(ushort8*)&Ah[wb + sloff[0]] = pack8(sreg[0]);
      if (act1) *(ushort8*)&Ah[wb + sloff[1]] = pack8(sreg[1]);
    }

#pragma unroll
    for (int ox = 0; ox < 3; ++ox) {
      const int p = (c + ox) & 1;         // static after full unroll
      // ---- prefetch next B batch (and sreg 2 chunks ahead at ox==2) ----
      if (ox < 2) {
#pragma unroll
        for (int oy = 0; oy < 3; ++oy) {
          const unsigned short* bp =
              W1b + ((((oy * 3 + ox + 1) * 12 + c) << 12)) + boff;
          bf[1 - p][oy][0] = *(const bf16x8*)bp;
          bf[1 - p][oy][1] = *(const bf16x8*)(bp + 512);
        }
      } else {
        if (c < 10) {
          const int off = (c + 2) << 5;
#pragma unroll
          for (int j = 0; j < 2; ++j) {
            if (svalid[j]) {
              *(float4*)&sreg[j][0] = *(const float4*)(x + soff[j] + off);
              *(float4*)&sreg[j][4] = *(const float4*)(x + soff[j] + off + 4);
            }
          }
        }
        if (c < 11) {
#pragma unroll
          for (int oy = 0; oy < 3; ++oy) {
            const unsigned short* bp =
                W1b + ((((oy * 3 + 0) * 12 + (c + 1)) << 12)) + boff;
            bf[1 - p][oy][0] = *(const bf16x8*)bp;
            bf[1 - p][oy][1] = *(const bf16x8*)(bp + 512);
          }
        }
      }
      // ---- MFMAs for this ox from the already-resident batch bf[p] ----
#pragma unroll
      for (int h = 0; h < 6; ++h) {
        const bf16x8 af =
            *(const bf16x8*)&Ah[rb + ((h * 18 + ox) << 3) + aoffl];
#pragma unroll
        for (int oy = 0; oy < 3; ++oy) {
          const int mi = h - oy;
          if (mi >= 0 && mi < 4) {
            acc[mi][0] = __builtin_amdgcn_mfma_f32_16x16x32_bf16(
                af, bf[p][oy][0], acc[mi][0], 0, 0, 0);
            acc[mi][1] = __builtin_amdgcn_mfma_f32_16x16x32_bf16(
                af, bf[p][oy][1], acc[mi][1], 0, 0, 0);
          }
        }
      }
    }
    __syncthreads();
  }

  // ---- epilogue: bias+relu, conv1x1 reduce over n, sigmoid ----
#pragma unroll
  for (int mi = 0; mi < 4; ++mi) {
#pragma unroll
    for (int r = 0; r < 4; ++r) {
      float h0 = fmaxf(acc[mi][0][r] + b1v0, 0.0f);
      float h1 = fmaxf(acc[mi][1][r] + b1v1, 0.0f);
      float v = h0 * w2v0 + h1 * w2v1;
      v += __shfl_xor(v, 1);
      v += __shfl_xor(v, 2);
      v += __shfl_xor(v, 4);
      v += __shfl_xor(v, 8);
      if (lr == 0) {
        int m = mi * 16 + g * 4 + r;  // pixel row = mi, pixel col = g*4+r
        hsum[m * 4 + w] = v;
      }
    }
  }
  __syncthreads();
  if (t < 64) {
    float s = hsum[t * 4 + 0] + hsum[t * 4 + 1] + hsum[t * 4 + 2] +
              hsum[t * 4 + 3] + b2[0];
    float sig = 1.0f / (1.0f + expf(-s));
    int prow = t >> 4, pcol = t & 15;
    out[((((img << 6) + ty0 + prow) << 6) + tx0 + pcol)] = sig;
  }
}

extern "C" void kernel_launch(void* const* d_in, const int* in_sizes, int n_in,
                              void* d_out, int out_size, void* d_ws, size_t ws_size,
                              hipStream_t stream) {
  const float* x  = (const float*)d_in[0];   // (32,64,64,384)
  const float* W1 = (const float*)d_in[1];   // (3,3,384,128)
  const float* b1 = (const float*)d_in[2];   // (128)
  const float* W2 = (const float*)d_in[3];   // (128)
  const float* b2 = (const float*)d_in[4];   // (1)
  float* out = (float*)d_out;                // (32,64,64,1)
  unsigned short* W1b = (unsigned short*)d_ws;  // 108*4096*2 = 884736 B

  prep_w1_kernel<<<108, 256, 0, stream>>>(W1, W1b);
  conv_fused_kernel<<<2048, 256, 0, stream>>>(x, W1b, b1, W2, b2, out);
}

// Round 7
// 335.875 us; speedup vs baseline: 1.3365x; 1.1109x over previous
//
#include <hip/hip_runtime.h>
#include <hip/hip_bf16.h>
#include <math.h>

// B=32, H=64, W=64, C_IN=384, C_HID=128
// conv3x3(pad1)+b1 -> relu -> conv1x1+b2 -> sigmoid, NHWC fp32.
// Implicit GEMM, halo-LDS (double-buffered), tap-sharing, BIG M:
//   per block: 16x16 output pixels (M=256), N=128, K=9*384. Grid 512 = 2/CU.
//   chunk loop (12 x 32ch): one barrier/chunk; halo 18x18 px x 32ch bf16 in
//   flat [px][32] layout (b128 reads/writes at the 8-access minimum);
//   staging split in 2 groups of 3 items interleaved between ox blocks.
//   Per wave-chunk: 288 MFMA vs 54 ds_read vs ~30 VMEM -> MFMA-dominated.

typedef __attribute__((ext_vector_type(8))) unsigned short ushort8;
typedef __attribute__((ext_vector_type(8))) __bf16 bf16x8;
typedef __attribute__((ext_vector_type(4))) float floatx4;

#define HPX 324            // 18*18 halo pixels
#define BUFE 10368         // HPX*32 elems per chunk buffer

static __device__ __forceinline__ unsigned short f2bf_rne(float f) {
  union { float f; unsigned int u; } x; x.f = f;
  unsigned int u = x.u;
  return (unsigned short)((u + 0x7fffu + ((u >> 16) & 1u)) >> 16);
}

static __device__ __forceinline__ ushort8 pack8(const float* v) {
  ushort8 r;
#pragma unroll
  for (int i = 0; i < 4; ++i) {
    __hip_bfloat162 p = __float22bfloat162_rn(make_float2(v[2 * i], v[2 * i + 1]));
    union { __hip_bfloat162 b; unsigned int u; } c;
    c.b = p;
    r[2 * i] = (unsigned short)(c.u & 0xffffu);
    r[2 * i + 1] = (unsigned short)(c.u >> 16);
  }
  return r;
}

// W1 (3,3,384,128 HWIO fp32) -> bf16 W1b[kk][n][c], kk=o*12+chunk, n=0..127, c=0..31.
__global__ void prep_w1_kernel(const float* __restrict__ W1,
                               unsigned short* __restrict__ W1b) {
  __shared__ unsigned short tile[32 * 128];
  const int kk = blockIdx.x;            // 0..107
  const int o = kk / 12;
  const int chunk = kk - o * 12;
  const float* src = W1 + (o * 384 + chunk * 32) * 128;  // [c][n], n contiguous
  const int t = threadIdx.x;
#pragma unroll
  for (int i = 0; i < 16; ++i) {
    int idx = t + i * 256;              // idx = c*128+n
    int c = idx >> 7;
    int n = idx & 127;
    tile[n * 32 + c] = f2bf_rne(src[idx]);
  }
  __syncthreads();
  unsigned short* dst = W1b + kk * 4096;
#pragma unroll
  for (int i = 0; i < 16; ++i) {
    int idx = t + i * 256;
    dst[idx] = tile[idx];
  }
}

__global__ __launch_bounds__(256, 2) void conv_fused_kernel(
    const float* __restrict__ x, const unsigned short* __restrict__ W1b,
    const float* __restrict__ b1, const float* __restrict__ W2,
    const float* __restrict__ b2, float* __restrict__ out) {
  __shared__ alignas(16) unsigned short Ah[2 * BUFE];  // 41472 B
  __shared__ float hsum[256 * 4];                      // 4096 B

  const int t = threadIdx.x;
  const int w = t >> 6;        // wave 0..3 -> n block [32w, 32w+32)
  const int lane = t & 63;
  const int g = lane >> 4;     // quad (k-sub)
  const int lr = lane & 15;

  const int img = blockIdx.x >> 4;       // 32 images
  const int tileId = blockIdx.x & 15;    // 4x4 grid of 16x16 tiles
  const int ty0 = (tileId >> 2) << 4;
  const int tx0 = (tileId & 3) << 4;

  // ---- staging plan: 1296 items (halo px 0..323 x sub 0..3), 8 ch each ----
  // item = t + 256*j, j=0..5 (j=5 active only t<16). LDS offset = item*8 elems
  // (flat [px][32ch] layout -> consecutive lanes write consecutive 16B: min-conflict).
  int svalid[6];
  int soff[6];
#pragma unroll
  for (int j = 0; j < 6; ++j) {
    int item = t + (j << 8);
    int px = item >> 2, sub = item & 3;
    int hy = (px * 57) >> 10;            // px/18 for px<1024
    int hx = px - hy * 18;
    int iy = ty0 + hy - 1, ix = tx0 + hx - 1;
    int v = (item < 1296) && ((unsigned)iy < 64u) && ((unsigned)ix < 64u);
    svalid[j] = v;
    int iyc = v ? iy : 0, ixc = v ? ix : 0;
    soff[j] = ((((img << 6) + iyc) << 6) + ixc) * 384 + sub * 8;
  }

  // B frag offset (elems): row n = w*32 + lr (+16 for ni=1), k-sub = g*8
  const int boff = ((w * 32 + lr) << 5) + (g << 3);
  // A frag lane part (elems): halo col lr (+ox), quad k-sub g*8
  const int aoffl = (lr << 5) + (g << 3);

  floatx4 acc[16][2] = {};  // pixel row = mi, pixel col = g*4+r, ch n = w*32+ni*16+lr

  const float b1v0 = b1[w * 32 + lr];
  const float b1v1 = b1[w * 32 + 16 + lr];
  const float w2v0 = W2[w * 32 + lr];
  const float w2v1 = W2[w * 32 + 16 + lr];

  float sr[3][8];

  // ---- prologue: stage chunk 0 into buf0 (two groups of 3 items) ----
#pragma unroll
  for (int grp = 0; grp < 2; ++grp) {
#pragma unroll
    for (int j = 0; j < 3; ++j) {
      const int jj = grp * 3 + j;
      if (svalid[jj]) {
        *(float4*)&sr[j][0] = *(const float4*)(x + soff[jj]);
        *(float4*)&sr[j][4] = *(const float4*)(x + soff[jj] + 4);
      } else {
#pragma unroll
        for (int e = 0; e < 8; ++e) sr[j][e] = 0.0f;
      }
    }
#pragma unroll
    for (int j = 0; j < 3; ++j) {
      const int jj = grp * 3 + j;
      if (jj < 5 || t < 16)
        *(ushort8*)&Ah[(t + (jj << 8)) << 3] = pack8(sr[j]);
    }
  }
  __syncthreads();

  for (int c = 0; c < 12; ++c) {
    const int rb = (c & 1) * BUFE;        // read buffer (chunk c)
    const int wb = BUFE - rb;             // write buffer (chunk c+1)
    const int choff = (c + 1) << 5;
    const bool pf = (c < 11);

#pragma unroll
    for (int ox = 0; ox < 3; ++ox) {
      // ---- staging interleave: write prev group / load next group ----
      if (ox == 0) {
        if (pf) {
#pragma unroll
          for (int j = 0; j < 3; ++j) {
            if (svalid[j]) {
              *(float4*)&sr[j][0] = *(const float4*)(x + soff[j] + choff);
              *(float4*)&sr[j][4] = *(const float4*)(x + soff[j] + choff + 4);
            } else {
#pragma unroll
              for (int e = 0; e < 8; ++e) sr[j][e] = 0.0f;
            }
          }
        }
      } else if (ox == 1) {
        if (pf) {
#pragma unroll
          for (int j = 0; j < 3; ++j)
            *(ushort8*)&Ah[wb + ((t + (j << 8)) << 3)] = pack8(sr[j]);
#pragma unroll
          for (int j = 0; j < 3; ++j) {
            const int jj = 3 + j;
            if (svalid[jj]) {
              *(float4*)&sr[j][0] = *(const float4*)(x + soff[jj] + choff);
              *(float4*)&sr[j][4] = *(const float4*)(x + soff[jj] + choff + 4);
            } else {
#pragma unroll
              for (int e = 0; e < 8; ++e) sr[j][e] = 0.0f;
            }
          }
        }
      } else {  // ox == 2
        if (pf) {
#pragma unroll
          for (int j = 0; j < 3; ++j) {
            const int jj = 3 + j;
            if (jj < 5 || t < 16)
              *(ushort8*)&Ah[wb + ((t + (jj << 8)) << 3)] = pack8(sr[j]);
          }
        }
      }

      // ---- B frags for this ox (6 x 16B from L2-resident W1b) ----
      bf16x8 bf[3][2];
#pragma unroll
      for (int oy = 0; oy < 3; ++oy) {
        const unsigned short* bp =
            W1b + (((oy * 3 + ox) * 12 + c) << 12) + boff;
        bf[oy][0] = *(const bf16x8*)bp;
        bf[oy][1] = *(const bf16x8*)(bp + 512);
      }

      // ---- tap-shared MFMAs: A-frag at halo row h feeds oy with mi=h-oy ----
#pragma unroll
      for (int h = 0; h < 18; ++h) {
        const bf16x8 af =
            *(const bf16x8*)&Ah[rb + ((h * 18 + ox) << 5) + aoffl];
#pragma unroll
        for (int oy = 0; oy < 3; ++oy) {
          const int mi = h - oy;
          if (mi >= 0 && mi < 16) {
            acc[mi][0] = __builtin_amdgcn_mfma_f32_16x16x32_bf16(
                af, bf[oy][0], acc[mi][0], 0, 0, 0);
            acc[mi][1] = __builtin_amdgcn_mfma_f32_16x16x32_bf16(
                af, bf[oy][1], acc[mi][1], 0, 0, 0);
          }
        }
      }
    }
    __syncthreads();
  }

  // ---- epilogue: bias+relu, conv1x1 reduce over n, sigmoid ----
#pragma unroll
  for (int mi = 0; mi < 16; ++mi) {
#pragma unroll
    for (int r = 0; r < 4; ++r) {
      float h0 = fmaxf(acc[mi][0][r] + b1v0, 0.0f);
      float h1 = fmaxf(acc[mi][1][r] + b1v1, 0.0f);
      float v = h0 * w2v0 + h1 * w2v1;
      v += __shfl_xor(v, 1);
      v += __shfl_xor(v, 2);
      v += __shfl_xor(v, 4);
      v += __shfl_xor(v, 8);
      if (lr == 0) {
        int m = mi * 16 + g * 4 + r;  // pixel row = mi, pixel col = g*4+r
        hsum[m * 4 + w] = v;
      }
    }
  }
  __syncthreads();
  {
    float s = hsum[t * 4 + 0] + hsum[t * 4 + 1] + hsum[t * 4 + 2] +
              hsum[t * 4 + 3] + b2[0];
    float sig = 1.0f / (1.0f + expf(-s));
    int prow = t >> 4, pcol = t & 15;
    out[((((img << 6) + ty0 + prow) << 6) + tx0 + pcol)] = sig;
  }
}

extern "C" void kernel_launch(void* const* d_in, const int* in_sizes, int n_in,
                              void* d_out, int out_size, void* d_ws, size_t ws_size,
                              hipStream_t stream) {
  const float* x  = (const float*)d_in[0];   // (32,64,64,384)
  const float* W1 = (const float*)d_in[1];   // (3,3,384,128)
  const float* b1 = (const float*)d_in[2];   // (128)
  const float* W2 = (const float*)d_in[3];   // (128)
  const float* b2 = (const float*)d_in[4];   // (1)
  float* out = (float*)d_out;                // (32,64,64,1)
  unsigned short* W1b = (unsigned short*)d_ws;  // 108*4096*2 = 884736 B

  prep_w1_kernel<<<108, 256, 0, stream>>>(W1, W1b);
  conv_fused_kernel<<<512, 256, 0, stream>>>(x, W1b, b1, W2, b2, out);
}